// Round 8
// baseline (65.893 us; speedup 1.0000x reference)
//
#include <hip/hip_runtime.h>
#include <hip/hip_bf16.h>
#include <stdint.h>

// QuantizedLinear: out[m][n] = (sum_k x[m][k]*W[n][k]) * scale + bias[n]
// M=256, K=4096, N=11008. W int8-valued -> exact in bf16; scale/bias f32 epilogue.
//
// R8 = R7 pipeline with BK=128 (NT=32): double work per sync epoch, halve
// barrier count; 2-iter lookaheads double in CYCLES (~1500cy > HBM latency).
//  - W: global->reg (4 int4/thread, 4-slot named reg ring, tile u in slot u&3,
//    loaded 4 iters ahead) -> cvt on write side -> 2x ds_write_b128 into a
//    5-slot bf16 LDS ring (272B row pitch: reads 2-way bank = free).
//  - A: packed bf16 frags (cvt_x pass), global->reg ping-pong, reloaded right
//    after consumption (gap ~2 iters). vmcnt NEVER drained; per-iter sync =
//    lgkmcnt(0) + raw s_barrier. FIFO check: writeW(t) waits on W(t+2) =
//    oldest outstanding load; nothing younger force-retired.

#define MM 256
#define NN 11008
#define KK 4096
#define BK 128
#define NT (KK / BK)       // 32
#define ROWB 272           // bf16 row pitch (256B data + 16B pad)
#define SLOTB (32 * ROWB)  // 8704 B per LDS slot
#define NSLOT 5

typedef __bf16 bf16x8 __attribute__((ext_vector_type(8)));
typedef float  f32x4  __attribute__((ext_vector_type(4)));

// ---- pass 1: x f32 [256][4096] -> bf16 packed in MFMA A-fragment order ----
// xf[(mb*128 + kb)*64 + l] = bf16x8 { x[mb*16 + (l&15)][kb*32 + (l>>4)*8 + j] }
__global__ void cvt_x_kernel(const float* __restrict__ x, bf16x8* __restrict__ xf) {
    int i  = blockIdx.x * 256 + threadIdx.x;   // 0..131071
    int l  = i & 63;
    int kb = (i >> 6) & 127;
    int mb = i >> 13;
    int m  = mb * 16 + (l & 15);
    int k  = kb * 32 + (l >> 4) * 8;
    const float* p = x + (size_t)m * KK + k;
    float4 v0 = *(const float4*)p;
    float4 v1 = *(const float4*)(p + 4);
    union { __bf16 b[8]; bf16x8 v; } t;
    t.b[0] = (__bf16)v0.x; t.b[1] = (__bf16)v0.y;
    t.b[2] = (__bf16)v0.z; t.b[3] = (__bf16)v0.w;
    t.b[4] = (__bf16)v1.x; t.b[5] = (__bf16)v1.y;
    t.b[6] = (__bf16)v1.z; t.b[7] = (__bf16)v1.w;
    xf[i] = t.v;
}

// ---- pass 2: GEMM. 256 thr (4 waves); wave w: m-rows [mh*128+w*32,+32) x 32 n ----
__global__ __launch_bounds__(256, 3) void qlin_gemm(
    const bf16x8* __restrict__ xf, const int* __restrict__ wq,
    const float* __restrict__ scale, const float* __restrict__ bias,
    float* __restrict__ out) {

    __shared__ __align__(16) char wsm[NSLOT * SLOTB];   // 43.5 KB

    const int tid  = threadIdx.x;
    const int lane = tid & 63;
    const int wid  = tid >> 6;          // 0..3
    const int nl   = lane & 15;
    const int qh   = lane >> 4;

    // XCD-paired block map: per XCD 43 n-strips x 2 m-halves, mh fastest.
    const int bid   = blockIdx.x;       // 0..687
    const int xcd   = bid & 7;
    const int seq   = bid >> 3;         // 0..85
    const int strip = xcd * 43 + (seq >> 1);
    const int mh    = seq & 1;
    const int n0    = strip * 32;

    // --- W staging: thread t -> tile-row r = t>>3, k-slot s = t&7 (16 ints) ---
    const int wr = tid >> 3;
    const int ws = tid & 7;
    const int* wsrc = wq + (size_t)(n0 + wr) * KK + ws * 16;
    const int wdst  = wr * ROWB + ws * 32;

    // --- B fragment read base: row = fn*16+nl; byte = row*272 + kb*64 + qh*16 ---
    const int brd0 = nl * ROWB + qh * 16;
    const int brd1 = (16 + nl) * ROWB + qh * 16;

    // --- A fragments (packed, per-wave-private): chunk c -> abase[(fmr*128+c)*64] ---
    const bf16x8* abase = xf + ((size_t)(mh * 8 + wid * 2) * 128) * 64 + lane;

    f32x4 acc[2][2] = {};
    int4   R0[4], R1[4], R2[4], R3[4];   // W reg ring: tile u in slot u&3
    bf16x8 AA[8], AB[8];                 // A ping-pong: tile u in buf u&1; [fmr*4+kb]

    auto loadW = [&](int4 (&r)[4], int t) {
        const int* p = wsrc + t * BK;
#pragma unroll
        for (int j = 0; j < 4; ++j)
            r[j] = *(const int4*)(p + j * 4);
    };
    auto loadA = [&](bf16x8 (&A)[8], int t) {
#pragma unroll
        for (int fmr = 0; fmr < 2; ++fmr)
#pragma unroll
            for (int kb = 0; kb < 4; ++kb)
                A[fmr * 4 + kb] = abase[((size_t)fmr * 128 + t * 4 + kb) * 64];
    };
    auto writeW = [&](const int4 (&r)[4], int slotoff) {
        union { __bf16 e[16]; bf16x8 v[2]; } c;
#pragma unroll
        for (int j = 0; j < 4; ++j) {
            c.e[j * 4 + 0] = (__bf16)(float)r[j].x;
            c.e[j * 4 + 1] = (__bf16)(float)r[j].y;
            c.e[j * 4 + 2] = (__bf16)(float)r[j].z;
            c.e[j * 4 + 3] = (__bf16)(float)r[j].w;
        }
        char* d = wsm + slotoff + wdst;
        *(bf16x8*)d = c.v[0];
        *(bf16x8*)(d + 16) = c.v[1];
    };
    auto compute = [&](const bf16x8 (&A)[8], int slotoff) {
        const char* B = wsm + slotoff;
#pragma unroll
        for (int kb = 0; kb < 4; ++kb) {
            bf16x8 b0 = *(const bf16x8*)(B + brd0 + kb * 64);
            bf16x8 b1 = *(const bf16x8*)(B + brd1 + kb * 64);
#pragma unroll
            for (int fmr = 0; fmr < 2; ++fmr) {
                acc[fmr][0] = __builtin_amdgcn_mfma_f32_16x16x32_bf16(
                    A[fmr * 4 + kb], b0, acc[fmr][0], 0, 0, 0);
                acc[fmr][1] = __builtin_amdgcn_mfma_f32_16x16x32_bf16(
                    A[fmr * 4 + kb], b1, acc[fmr][1], 0, 0, 0);
            }
        }
    };

    // ---- prologue: W(0..3) -> reg ring; A(0),A(1); tiles 0,1 -> LDS slots 0,1 ----
    loadW(R0, 0); loadW(R1, 1); loadW(R2, 2); loadW(R3, 3);
    loadA(AA, 0); loadA(AB, 1);
    writeW(R0, 0 * SLOTB);
    writeW(R1, 1 * SLOTB);
    asm volatile("s_waitcnt lgkmcnt(0)" ::: "memory");
    __builtin_amdgcn_s_barrier();

    int srd = 0 * SLOTB;   // slot holding tile t (read)
    int swr = 2 * SLOTB;   // slot receiving tile t+2 (write)

    // ---- iter t: loadW(W(t+4)); writeW(regs tile t+2, 2 iters old);
    //              compute(t); loadA(A(t+2) into just-freed buf); lgkm(0); barrier ----
#define STEP(T, WL, WS, AB_)                                         \
    {                                                                \
        const int t_ = (T);                                          \
        loadW(WL, (t_ + 4 < NT) ? t_ + 4 : NT - 1);                  \
        writeW(WS, swr);                                             \
        compute(AB_, srd);                                           \
        loadA(AB_, (t_ + 2 < NT) ? t_ + 2 : NT - 1);                 \
        asm volatile("s_waitcnt lgkmcnt(0)" ::: "memory");           \
        __builtin_amdgcn_s_barrier();                                \
        srd += SLOTB; if (srd == NSLOT * SLOTB) srd = 0;             \
        swr += SLOTB; if (swr == NSLOT * SLOTB) swr = 0;             \
    }

#pragma unroll 1
    for (int tq = 0; tq < NT / 4; ++tq) {
        const int t0 = tq * 4;
        STEP(t0 + 0, R0, R2, AA)   // reload R0 <- W(t+4); publish tile t+2 (R2)
        STEP(t0 + 1, R1, R3, AB)
        STEP(t0 + 2, R2, R0, AA)
        STEP(t0 + 3, R3, R1, AB)
    }
#undef STEP

    // ---- epilogue: D layout col=lane&15, row=qh*4+r; y = acc*scale + bias ----
    const float sc = scale[0];
    const int erow0 = qh * 4;
#pragma unroll
    for (int fn = 0; fn < 2; ++fn) {
        const int n = n0 + fn * 16 + nl;
        const float bv = bias[n];
#pragma unroll
        for (int fmr = 0; fmr < 2; ++fmr) {
            const int m = mh * 128 + wid * 32 + fmr * 16 + erow0;
#pragma unroll
            for (int r = 0; r < 4; ++r)
                out[(size_t)(m + r) * NN + n] = acc[fmr][fn][r] * sc + bv;
        }
    }
}

extern "C" void kernel_launch(void* const* d_in, const int* in_sizes, int n_in,
                              void* d_out, int out_size, void* d_ws, size_t ws_size,
                              hipStream_t stream) {
    const float* x     = (const float*)d_in[0];
    const int*   wq    = (const int*)d_in[1];
    const float* scale = (const float*)d_in[2];
    const float* bias  = (const float*)d_in[3];
    float* out = (float*)d_out;
    bf16x8* xf = (bf16x8*)d_ws;   // 2 MB packed-A scratch

    cvt_x_kernel<<<dim3(MM * KK / (256 * 8)), dim3(256), 0, stream>>>(x, xf);
    qlin_gemm<<<dim3(688), dim3(256), 0, stream>>>(xf, wq, scale, bias, out);
}